// Round 6
// baseline (353.944 us; speedup 1.0000x reference)
//
#include <hip/hip_runtime.h>
#include <math.h>

#define EPS 1e-5f

typedef __attribute__((ext_vector_type(8))) short bf16x8;
typedef __attribute__((ext_vector_type(4))) float f32x4;

__device__ __forceinline__ unsigned short f2bf(float f) {
    unsigned int u = __float_as_uint(f);
    u += 0x7fff + ((u >> 16) & 1);            // round-to-nearest-even
    return (unsigned short)(u >> 16);
}
__device__ __forceinline__ float bf2f(unsigned short h) {
    return __uint_as_float(((unsigned int)h) << 16);
}
__device__ __forceinline__ float lof(unsigned int u) {
    return __uint_as_float(u << 16);
}
__device__ __forceinline__ float hif(unsigned int u) {
    return __uint_as_float(u & 0xffff0000u);
}
__device__ __forceinline__ void async16(void* lds, const void* g) {
    __builtin_amdgcn_global_load_lds(
        (const __attribute__((address_space(1))) unsigned int*)g,
        (__attribute__((address_space(3))) unsigned int*)lds, 16, 0, 0);
}

// ---------------- prep: everything weight-side in ONE kernel ----------------
__global__ __launch_bounds__(256) void prep_all(
    const float* __restrict__ lnfg, const float* __restrict__ lnfb,
    const float* __restrict__ wq, const float* __restrict__ bq,
    const float* __restrict__ efpw, const float* __restrict__ efpb,
    const float* __restrict__ lngg, const float* __restrict__ lngb,
    const float* __restrict__ wk, const float* __restrict__ bk,
    const float* __restrict__ wv, const float* __restrict__ bv,
    const float* __restrict__ wo, const float* __restrict__ outcw,
    const float* __restrict__ outcb, const float* __restrict__ bng,
    const float* __restrict__ bnb, const float* __restrict__ bnm,
    const float* __restrict__ bnv, const float* __restrict__ dwk,
    unsigned short* __restrict__ Wb1t, unsigned short* __restrict__ Wb2t,
    unsigned short* __restrict__ Wot, unsigned short* __restrict__ Woc,
    float* __restrict__ dwt,
    float* __restrict__ cs1, float* __restrict__ cst1,
    float* __restrict__ cs2, float* __restrict__ cst2,
    float* __restrict__ scv, float* __restrict__ shv)
{
    int idx = blockIdx.x * 256 + threadIdx.x;
    if (idx < 262144) {                       // Wb1t [n=512][k=512]: q | efp
        int n = idx >> 9, k = idx & 511;
        float v = (n < 256) ? lnfg[k] * wq[k * 256 + n]
                            : efpw[(size_t)(n - 256) * 512 + k];
        Wb1t[idx] = f2bf(v);
    } else if (idx < 327680) {                // Wb2t [n=256][k=256]: k only
        int j = idx - 262144; int n = j >> 8, k = j & 255;
        Wb2t[j] = f2bf(lngg[k] * wk[k * 256 + n]);
    } else if (idx < 393216) {                // Wot [256][256] = wo^T
        int j = idx - 327680; int n = j >> 8, k = j & 255;
        Wot[j] = f2bf(wo[k * 256 + n]);
    } else if (idx < 458752) {                // Woc [256][256] = outc_w
        int j = idx - 393216;
        Woc[j] = f2bf(outcw[j]);
    } else if (idx < 461056) {                // dwt [tap][ch]
        int j = idx - 458752; int tap = j >> 8, ch = j & 255;
        dwt[j] = dwk[ch * 9 + tap];
    } else if (idx < 462336) {                // column constants
        int j = idx - 461056;
        if (j < 256) {
            int n = j; float cs = 0.f, ct = 0.f;
            for (int k = 0; k < 512; k++) {
                float w = wq[k * 256 + n];
                cs += lnfg[k] * w; ct += lnfb[k] * w;
            }
            cs1[n] = cs; cst1[n] = ct + bq[n];
        } else if (j < 512) {
            cs1[j] = 0.f; cst1[j] = efpb[j - 256];
        } else if (j < 768) {
            int n = j - 512; float cs = 0.f, ct = 0.f;
            for (int k = 0; k < 256; k++) {
                float w = wk[k * 256 + n];
                cs += lngg[k] * w; ct += lngb[k] * w;
            }
            cs2[n] = cs; cst2[n] = ct + bk[n];
        } else if (j < 1024) {
            int n = j - 768; float cs = 0.f, ct = 0.f;
            for (int k = 0; k < 256; k++) {
                float w = wv[k * 256 + n];
                cs += lngg[k] * w; ct += lngb[k] * w;
            }
            cs2[256 + n] = cs; cst2[256 + n] = ct + bv[n];
        } else {
            int n = j - 1024;
            float s = bng[n] * rsqrtf(bnv[n] + EPS);
            scv[n] = s;
            shv[n] = (outcb[n] - bnm[n]) * s + bnb[n];
        }
    }
}

// ------- NCHW fp32 -> [M][C] bf16 transpose, partial LN stats (no atomics) --
__global__ __launch_bounds__(256) void transpose_fg(
    const float* __restrict__ ef, const float* __restrict__ eg,
    unsigned short* __restrict__ ef_bf, unsigned short* __restrict__ eg_bf,
    float* __restrict__ pf, float* __restrict__ pfq,
    float* __restrict__ pg, float* __restrict__ pgq)
{
    __shared__ float tile[64][65];
    __shared__ float psum[4][64], pss[4][64];
    int id = blockIdx.x;
    const float* src; unsigned short* dst; float* ps; float* pq;
    int C, cblk, b, p0;
    if (id < 4096) {
        src = ef; dst = ef_bf; ps = pf; pq = pfq; C = 512;
        p0 = (id & 63) * 64; cblk = (id >> 6) & 7; b = id >> 9;
    } else {
        id -= 4096;
        src = eg; dst = eg_bf; ps = pg; pq = pgq; C = 256;
        p0 = (id & 63) * 64; cblk = (id >> 6) & 3; b = id >> 8;
    }
    int c0 = cblk * 64;
    const float* s = src + ((size_t)b * C + c0) * 4096 + p0;
    int t = threadIdx.x;
    int lane = t & 63, grp = t >> 6;
#pragma unroll
    for (int i = 0; i < 16; i++) {
        int c = i * 4 + grp;
        tile[c][lane] = s[(size_t)c * 4096 + lane];
    }
    __syncthreads();
    unsigned short* d = dst + ((size_t)(b * 4096 + p0)) * C + c0;
#pragma unroll
    for (int i = 0; i < 16; i++) {
        int p = i * 4 + grp;
        d[(size_t)p * C + lane] = f2bf(tile[lane][p]);
    }
    float sm = 0.f, sq = 0.f;
#pragma unroll
    for (int j = 0; j < 16; j++) {
        float v = tile[grp * 16 + j][lane];
        sm += v; sq += v * v;
    }
    psum[grp][lane] = sm; pss[grp][lane] = sq;
    __syncthreads();
    if (t < 64) {
        float fs = psum[0][t] + psum[1][t] + psum[2][t] + psum[3][t];
        float fq = pss[0][t] + pss[1][t] + pss[2][t] + pss[3][t];
        ps[cblk * 32768 + b * 4096 + p0 + t] = fs;
        pq[cblk * 32768 + b * 4096 + p0 + t] = fq;
    }
}

__global__ __launch_bounds__(256) void ln_finalize(
    const float* __restrict__ pf, const float* __restrict__ pfq,
    const float* __restrict__ pg, const float* __restrict__ pgq,
    float* __restrict__ mf, float* __restrict__ rf,
    float* __restrict__ mg, float* __restrict__ rg)
{
    int gp = blockIdx.x * 256 + threadIdx.x;
    float s = 0.f, q = 0.f;
#pragma unroll
    for (int i = 0; i < 8; i++) { s += pf[i * 32768 + gp]; q += pfq[i * 32768 + gp]; }
    float m = s * (1.f / 512.f);
    float v = q * (1.f / 512.f) - m * m;
    mf[gp] = m; rf[gp] = rsqrtf(v + EPS);
    s = 0.f; q = 0.f;
#pragma unroll
    for (int i = 0; i < 4; i++) { s += pg[i * 32768 + gp]; q += pgq[i * 32768 + gp]; }
    m = s * (1.f / 256.f);
    v = q * (1.f / 256.f) - m * m;
    mg[gp] = m; rg[gp] = rsqrtf(v + EPS);
}

// ---------------- MFMA GEMM core (m97-style, LDS-staged) --------------------
template<int K>
__device__ __forceinline__ void mfma_core(
    const unsigned short* __restrict__ A, const unsigned short* __restrict__ Bt,
    int m0, int n0, unsigned short* As, unsigned short* Bs, f32x4 acc[4][4])
{
    const int tid = threadIdx.x;
    const int wave = tid >> 6, lane = tid & 63;
    const int wm = (wave & 1) * 64, wn = (wave >> 1) * 64;
#pragma unroll
    for (int i = 0; i < 4; i++)
#pragma unroll
        for (int j = 0; j < 4; j++) acc[i][j] = (f32x4){0.f, 0.f, 0.f, 0.f};

    const int srow = wave * 32 + (lane >> 3);
    const int sg = (lane & 7) ^ ((lane >> 3) & 7);
    const unsigned short* ga = A + (size_t)(m0 + srow) * K + sg * 8;
    const unsigned short* gb = Bt + (size_t)(n0 + srow) * K + sg * 8;

    for (int k0 = 0; k0 < K; k0 += 64) {
#pragma unroll
        for (int t = 0; t < 4; t++) {
            async16(As + (wave * 32 + t * 8) * 64, ga + (size_t)t * 8 * K + k0);
            async16(Bs + (wave * 32 + t * 8) * 64, gb + (size_t)t * 8 * K + k0);
        }
        __syncthreads();
#pragma unroll
        for (int ks = 0; ks < 2; ks++) {
            bf16x8 af[4], bfr[4];
            int kb = ks * 4 + (lane >> 4);
            int slot = (kb ^ (lane & 7)) * 8;
#pragma unroll
            for (int i = 0; i < 4; i++) {
                int m = wm + i * 16 + (lane & 15);
                af[i] = *(const bf16x8*)&As[m * 64 + slot];
                int n = wn + i * 16 + (lane & 15);
                bfr[i] = *(const bf16x8*)&Bs[n * 64 + slot];
            }
#pragma unroll
            for (int i = 0; i < 4; i++)
#pragma unroll
                for (int j = 0; j < 4; j++)
                    acc[i][j] = __builtin_amdgcn_mfma_f32_16x16x32_bf16(
                        af[i], bfr[j], acc[i][j], 0, 0, 0);
        }
        __syncthreads();
    }
}

// ---------------- GEMM1: ef_bf x Wb1t -> q (bf16, LN affine) | efp (bf16) ---
__global__ __launch_bounds__(256) void gemm1_mfma(
    const unsigned short* __restrict__ ef_bf, const unsigned short* __restrict__ Wb1t,
    const float* __restrict__ cs1, const float* __restrict__ cst1,
    const float* __restrict__ mf, const float* __restrict__ rf,
    unsigned short* __restrict__ qbuf, unsigned short* __restrict__ efpbuf)
{
    __shared__ unsigned short As[8192], Bs[8192];
    f32x4 acc[4][4];
    int m0 = blockIdx.x * 128, n0 = blockIdx.y * 128;
    mfma_core<512>(ef_bf, Wb1t, m0, n0, As, Bs, acc);
    int lane = threadIdx.x & 63, wave = threadIdx.x >> 6;
    int wm = (wave & 1) * 64, wn = (wave >> 1) * 64;
    bool isq = (n0 < 256);
#pragma unroll
    for (int i = 0; i < 4; i++) {
#pragma unroll
        for (int r = 0; r < 4; r++) {
            int gm = m0 + wm + i * 16 + ((lane >> 4) * 4) + r;
            float mean = mf[gm], rs = rf[gm];
#pragma unroll
            for (int j = 0; j < 4; j++) {
                int n = n0 + wn + j * 16 + (lane & 15);
                float v = acc[i][j][r];
                if (isq) {
                    float o = rs * (v - mean * cs1[n]) + cst1[n];
                    qbuf[(size_t)gm * 256 + n] = f2bf(o);
                } else {
                    efpbuf[(size_t)gm * 256 + (n - 256)] = f2bf(v + cst1[n]);
                }
            }
        }
    }
}

// ---------------- GEMM2k: eg_bf x Wb2t -> kfull only (bf16, LN affine) ------
__global__ __launch_bounds__(256) void gemm2k_mfma(
    const unsigned short* __restrict__ eg_bf, const unsigned short* __restrict__ Wb2t,
    const float* __restrict__ cs2, const float* __restrict__ cst2,
    const float* __restrict__ mg, const float* __restrict__ rg,
    unsigned short* __restrict__ kfull)
{
    __shared__ unsigned short As[8192], Bs[8192];
    f32x4 acc[4][4];
    int m0 = blockIdx.x * 128, n0 = blockIdx.y * 128;
    mfma_core<256>(eg_bf, Wb2t, m0, n0, As, Bs, acc);
    int lane = threadIdx.x & 63, wave = threadIdx.x >> 6;
    int wm = (wave & 1) * 64, wn = (wave >> 1) * 64;
#pragma unroll
    for (int i = 0; i < 4; i++) {
#pragma unroll
        for (int r = 0; r < 4; r++) {
            int gm = m0 + wm + i * 16 + ((lane >> 4) * 4) + r;
            float mean = mg[gm], rs = rg[gm];
#pragma unroll
            for (int j = 0; j < 4; j++) {
                int n = n0 + wn + j * 16 + (lane & 15);
                float o = rs * (acc[i][j][r] - mean * cs2[n]) + cst2[n];
                kfull[(size_t)gm * 256 + n] = f2bf(o);
            }
        }
    }
}

// ------ FUSED GEMM3+GEMM4: block = 64 positions, global-direct fragments ----
// Stage1: ea[64][256] = (comb @ Wot + bo) * efp  -> LDS (XOR-swizzled)
// Stage2: out[co][pos] = ReLU(BN(Woc @ ea^T))   -> NCHW store
__global__ __launch_bounds__(256) void gemm34_mfma(
    const unsigned short* __restrict__ comb, const unsigned short* __restrict__ Wot,
    const float* __restrict__ bo, const unsigned short* __restrict__ efp,
    const unsigned short* __restrict__ Woc,
    const float* __restrict__ scv, const float* __restrict__ shv,
    float* __restrict__ outp)
{
    __shared__ unsigned short ea[64 * 256];     // 32 KB
    int wave = threadIdx.x >> 6, lane = threadIdx.x & 63;
    int fr = lane & 15, quad = lane >> 4;
    int m0 = blockIdx.x * 64;                   // global position base

    // ---- stage 1 ----
    f32x4 acc[4][4];
#pragma unroll
    for (int i = 0; i < 4; i++)
#pragma unroll
        for (int j = 0; j < 4; j++) acc[i][j] = (f32x4){0.f, 0.f, 0.f, 0.f};
#pragma unroll
    for (int ks = 0; ks < 8; ks++) {
        bf16x8 af[4], bfr[4];
#pragma unroll
        for (int i = 0; i < 4; i++)
            af[i] = *(const bf16x8*)(comb +
                     (size_t)(m0 + i * 16 + fr) * 256 + ks * 32 + quad * 8);
#pragma unroll
        for (int j = 0; j < 4; j++)
            bfr[j] = *(const bf16x8*)(Wot +
                     (size_t)(wave * 64 + j * 16 + fr) * 256 + ks * 32 + quad * 8);
#pragma unroll
        for (int i = 0; i < 4; i++)
#pragma unroll
            for (int j = 0; j < 4; j++)
                acc[i][j] = __builtin_amdgcn_mfma_f32_16x16x32_bf16(
                    af[i], bfr[j], acc[i][j], 0, 0, 0);
    }
    // epilogue: +bo, *efp, bf16 -> LDS [pos][oc] swizzled
#pragma unroll
    for (int j = 0; j < 4; j++) {
        int oc = wave * 64 + j * 16 + fr;
        float bb = bo[oc];
        int g = oc >> 3, sub = oc & 7;
#pragma unroll
        for (int i = 0; i < 4; i++) {
#pragma unroll
            for (int r = 0; r < 4; r++) {
                int pl = i * 16 + quad * 4 + r;
                float o = (acc[i][j][r] + bb) * bf2f(efp[(size_t)(m0 + pl) * 256 + oc]);
                ea[pl * 256 + ((g ^ (pl & 7)) << 3) + sub] = f2bf(o);
            }
        }
    }
    __syncthreads();

    // ---- stage 2 ----
    f32x4 acc2[4][4];
#pragma unroll
    for (int i = 0; i < 4; i++)
#pragma unroll
        for (int j = 0; j < 4; j++) acc2[i][j] = (f32x4){0.f, 0.f, 0.f, 0.f};
#pragma unroll
    for (int ks = 0; ks < 8; ks++) {
        bf16x8 af[4], bfr[4];
#pragma unroll
        for (int i = 0; i < 4; i++)
            af[i] = *(const bf16x8*)(Woc +
                     (size_t)(wave * 64 + i * 16 + fr) * 256 + ks * 32 + quad * 8);
        int g = ks * 4 + quad;
#pragma unroll
        for (int j = 0; j < 4; j++) {
            int pos = j * 16 + fr;
            bfr[j] = *(const bf16x8*)&ea[pos * 256 + ((g ^ (fr & 7)) << 3)];
        }
#pragma unroll
        for (int i = 0; i < 4; i++)
#pragma unroll
            for (int j = 0; j < 4; j++)
                acc2[i][j] = __builtin_amdgcn_mfma_f32_16x16x32_bf16(
                    af[i], bfr[j], acc2[i][j], 0, 0, 0);
    }
    int b_ = m0 >> 12, p0 = m0 & 4095;
#pragma unroll
    for (int i = 0; i < 4; i++) {
#pragma unroll
        for (int r = 0; r < 4; r++) {
            int co = wave * 64 + i * 16 + quad * 4 + r;
            float s = scv[co], hh = shv[co];
#pragma unroll
            for (int j = 0; j < 4; j++) {
                int p = p0 + j * 16 + fr;
                float o = fmaxf(fmaf(acc2[i][j][r], s, hh), 0.f);
                outp[(size_t)b_ * 1048576 + (size_t)co * 4096 + p] = o;
            }
        }
    }
}

// ------ pool phase: blocks 0..127 k-maxpool; 128..255 weighted v-pool -------
__global__ __launch_bounds__(256) void pool_phase(
    const unsigned short* __restrict__ kfull, const unsigned short* __restrict__ eg_bf,
    const float* __restrict__ rg, const float* __restrict__ mg,
    unsigned short* __restrict__ kpb, float* __restrict__ s1,
    float* __restrict__ s0)
{
    __shared__ float smem[2048];
    int id = blockIdx.x;
    int t = threadIdx.x;
    if (id < 128) {
        // ---- k max pool: (b, cell) ----
        int b = id >> 4, cell = id & 15;
        int hp = cell >> 2, wp = cell & 3;
        int g8 = t & 31, rr = t >> 5;
        float kmx[8];
#pragma unroll
        for (int j = 0; j < 8; j++) kmx[j] = -3.402823466e38f;
#pragma unroll
        for (int rsub = 0; rsub < 2; rsub++) {
            int r = rr * 2 + rsub;
            int prow = (hp * 16 + r) * 64 + wp * 16;
            for (int cl = 0; cl < 16; cl++) {
                size_t basei = ((size_t)(b * 4096 + prow + cl)) * 256 + g8 * 8;
                uint4 kv = *(const uint4*)(kfull + basei);
                kmx[0] = fmaxf(kmx[0], lof(kv.x)); kmx[1] = fmaxf(kmx[1], hif(kv.x));
                kmx[2] = fmaxf(kmx[2], lof(kv.y)); kmx[3] = fmaxf(kmx[3], hif(kv.y));
                kmx[4] = fmaxf(kmx[4], lof(kv.z)); kmx[5] = fmaxf(kmx[5], hif(kv.z));
                kmx[6] = fmaxf(kmx[6], lof(kv.w)); kmx[7] = fmaxf(kmx[7], hif(kv.w));
            }
        }
#pragma unroll
        for (int j = 0; j < 8; j++) smem[rr * 256 + g8 * 8 + j] = kmx[j];
        __syncthreads();
        float m = smem[t];
#pragma unroll
        for (int r2 = 1; r2 < 8; r2++) m = fmaxf(m, smem[r2 * 256 + t]);
        kpb[(size_t)(b * 16 + cell) * 256 + t] = f2bf(m);   // lossless
    } else {
        // ---- weighted v-pool partials from eg_bf: (b, cell), thread = ch ---
        int id2 = id - 128;
        int b = id2 >> 4, cell = id2 & 15;
        int hp = cell >> 2, wp = cell & 3;
        // s0 partial: thread t <-> position (r = t>>4, c = t&15)
        int pt = b * 4096 + (hp * 16 + (t >> 4)) * 64 + wp * 16 + (t & 15);
        smem[t] = rg[pt] * mg[pt];
        float accv = 0.f;
        for (int r = 0; r < 16; r++) {
            int prow = b * 4096 + (hp * 16 + r) * 64 + wp * 16;
#pragma unroll 4
            for (int c2 = 0; c2 < 16; c2++) {
                int p = prow + c2;
                accv = fmaf(rg[p], bf2f(eg_bf[(size_t)p * 256 + t]), accv);
            }
        }
        s1[(size_t)id2 * 256 + t] = accv;
        __syncthreads();
        if (t < 64) {
            float v = smem[t] + smem[t + 64] + smem[t + 128] + smem[t + 192];
#pragma unroll
            for (int off = 32; off >= 1; off >>= 1) v += __shfl_down(v, off);
            if (t == 0) s0[id2] = v;
        }
    }
}

// ------- v-pool mini-GEMM: vp[cell][n] from s1/s0 (fp32) --------------------
__global__ __launch_bounds__(256) void vpool_gemm(
    const float* __restrict__ s1, const float* __restrict__ s0,
    const float* __restrict__ lngg, const float* __restrict__ wv,
    const float* __restrict__ cs2, const float* __restrict__ cst2,
    float* __restrict__ vp)
{
    int cell = blockIdx.x;        // 0..127 = b*16+cell
    int n = threadIdx.x;
    const float* s1r = s1 + (size_t)cell * 256;
    float acc = 0.f;
    for (int c = 0; c < 256; c++)
        acc = fmaf(lngg[c] * s1r[c], wv[c * 256 + n], acc);
    vp[(size_t)cell * 256 + n] = acc * (1.f / 256.f)
        - (s0[cell] * (1.f / 256.f)) * cs2[256 + n] + cst2[256 + n];
}

// ---- combined = attn@vp + dw3x3(q): scores fused, no global attns ----------
__global__ __launch_bounds__(256) void combined_dw(
    const unsigned short* __restrict__ qbuf, const unsigned short* __restrict__ kpb,
    const float* __restrict__ vp, const float* __restrict__ dwt,
    unsigned short* __restrict__ combined)
{
    __shared__ float attns[256];          // 16 pos x 16 cells
    int wave = threadIdx.x >> 6, lane = threadIdx.x & 63;
    int id = blockIdx.x;                  // 2048
    int b = id & 7, seg = id >> 3;        // batch pinned per XCD
    int pidx0 = seg * 16;

    if (wave == 0) {
        int fr = lane & 15, quad = lane >> 4;
        const unsigned short* qrow = qbuf + (size_t)(b * 4096 + pidx0 + fr) * 256 + quad * 8;
        const unsigned short* krow = kpb + (size_t)(b * 16 + fr) * 256 + quad * 8;
        f32x4 sacc = {0.f, 0.f, 0.f, 0.f};
#pragma unroll
        for (int ks = 0; ks < 8; ks++) {
            bf16x8 af = *(const bf16x8*)(qrow + ks * 32);
            bf16x8 bf_ = *(const bf16x8*)(krow + ks * 32);
            sacc = __builtin_amdgcn_mfma_f32_16x16x32_bf16(af, bf_, sacc, 0, 0, 0);
        }
#pragma unroll
        for (int r = 0; r < 4; r++) {
            float s = sacc[r] * 0.0625f;  // HID^-0.5
            float mx = s;
#pragma unroll
            for (int off = 8; off >= 1; off >>= 1) mx = fmaxf(mx, __shfl_xor(mx, off));
            float e = __expf(s - mx);
            float sum = e;
#pragma unroll
            for (int off = 8; off >= 1; off >>= 1) sum += __shfl_xor(sum, off);
            attns[(quad * 4 + r) * 16 + fr] = e / sum;
        }
    }
    __syncthreads();

    int pidx = pidx0 + wave * 4;
    int h = pidx >> 6, w0 = pidx & 63;
    int o4 = lane * 4;

    float4 kreg[9];
#pragma unroll
    for (int tap = 0; tap < 9; tap++)
        kreg[tap] = *(const float4*)&dwt[tap * 256 + o4];

    float4 acc[4];
#pragma unroll
    for (int i = 0; i < 4; i++) acc[i] = (float4){0.f, 0.f, 0.f, 0.f};

    const float* arow = attns + (wave * 4) * 16;
#pragma unroll
    for (int c = 0; c < 16; c++) {
        float4 v = *(const float4*)&vp[(size_t)(b * 16 + c) * 256 + o4];
#pragma unroll
        for (int i = 0; i < 4; i++) {
            float a = arow[i * 16 + c];
            acc[i].x = fmaf(a, v.x, acc[i].x); acc[i].y = fmaf(a, v.y, acc[i].y);
            acc[i].z = fmaf(a, v.z, acc[i].z); acc[i].w = fmaf(a, v.w, acc[i].w);
        }
    }
#pragma unroll
    for (int dy = 0; dy < 3; dy++) {
        int hh = h + dy - 1;
        if (hh < 0 || hh > 63) continue;
        const unsigned short* qr = qbuf + ((size_t)(b * 4096 + hh * 64)) * 256;
        float4 ft[6];
#pragma unroll
        for (int c = 0; c < 6; c++) {
            int xx = w0 - 1 + c;
            if (xx < 0 || xx > 63) {
                ft[c] = (float4){0.f, 0.f, 0.f, 0.f};
            } else {
                uint2 qa = *(const uint2*)(qr + (size_t)xx * 256 + o4);
                ft[c] = (float4){lof(qa.x), hif(qa.x), lof(qa.y), hif(qa.y)};
            }
        }
#pragma unroll
        for (int dx = 0; dx < 3; dx++) {
            float4 kk = kreg[dy * 3 + dx];
#pragma unroll
            for (int i = 0; i < 4; i++) {
                float4 qv = ft[i + dx];
                acc[i].x = fmaf(qv.x, kk.x, acc[i].x);
                acc[i].y = fmaf(qv.y, kk.y, acc[i].y);
                acc[i].z = fmaf(qv.z, kk.z, acc[i].z);
                acc[i].w = fmaf(qv.w, kk.w, acc[i].w);
            }
        }
    }
#pragma unroll
    for (int i = 0; i < 4; i++) {
        uint2 pk;
        pk.x = (unsigned)f2bf(acc[i].x) | ((unsigned)f2bf(acc[i].y) << 16);
        pk.y = (unsigned)f2bf(acc[i].z) | ((unsigned)f2bf(acc[i].w) << 16);
        *(uint2*)(combined + ((size_t)(b * 4096 + pidx + i)) * 256 + o4) = pk;
    }
}

// ---------------------------------------------------------------------------
extern "C" void kernel_launch(void* const* d_in, const int* in_sizes, int n_in,
                              void* d_out, int out_size, void* d_ws, size_t ws_size,
                              hipStream_t stream)
{
    const float* e_f   = (const float*)d_in[0];
    const float* e_g   = (const float*)d_in[1];
    const float* lnfg  = (const float*)d_in[4];
    const float* lnfb  = (const float*)d_in[5];
    const float* lngg  = (const float*)d_in[6];
    const float* lngb  = (const float*)d_in[7];
    const float* wq    = (const float*)d_in[8];
    const float* bq    = (const float*)d_in[9];
    const float* wk    = (const float*)d_in[10];
    const float* bk    = (const float*)d_in[11];
    const float* wv    = (const float*)d_in[12];
    const float* bv    = (const float*)d_in[13];
    const float* wo    = (const float*)d_in[14];
    const float* bo    = (const float*)d_in[15];
    const float* dwk   = (const float*)d_in[16];
    const float* efpw  = (const float*)d_in[17];
    const float* efpb  = (const float*)d_in[18];
    const float* outcw = (const float*)d_in[19];
    const float* outcb = (const float*)d_in[20];
    const float* bng   = (const float*)d_in[21];
    const float* bnb   = (const float*)d_in[22];
    const float* bnm   = (const float*)d_in[23];
    const float* bnv   = (const float*)d_in[24];
    float* outp = (float*)d_out;

    char* base = (char*)d_ws;
    auto alloc = [&](size_t bytes) -> char* {
        char* r = base; base += (bytes + 255) & ~(size_t)255; return r;
    };
    float* pf    = (float*)alloc(8 * 32768 * 4);
    float* pfq   = (float*)alloc(8 * 32768 * 4);
    float* pg    = (float*)alloc(4 * 32768 * 4);
    float* pgq   = (float*)alloc(4 * 32768 * 4);
    float* mf    = (float*)alloc(32768 * 4);
    float* rf    = (float*)alloc(32768 * 4);
    float* mg    = (float*)alloc(32768 * 4);
    float* rg    = (float*)alloc(32768 * 4);
    float* cs1   = (float*)alloc(512 * 4);
    float* cst1  = (float*)alloc(512 * 4);
    float* cs2   = (float*)alloc(512 * 4);
    float* cst2  = (float*)alloc(512 * 4);
    float* scv   = (float*)alloc(256 * 4);
    float* shv   = (float*)alloc(256 * 4);
    float* dwt   = (float*)alloc(9 * 256 * 4);
    unsigned short* Wb1t = (unsigned short*)alloc(262144 * 2);
    unsigned short* Wb2t = (unsigned short*)alloc(65536 * 2);
    unsigned short* Wot  = (unsigned short*)alloc(65536 * 2);
    unsigned short* Woc  = (unsigned short*)alloc(65536 * 2);
    unsigned short* ef_bf = (unsigned short*)alloc((size_t)32768 * 512 * 2);
    unsigned short* eg_bf = (unsigned short*)alloc((size_t)32768 * 256 * 2);
    unsigned short* qbuf  = (unsigned short*)alloc((size_t)32768 * 256 * 2);
    unsigned short* efpbuf = (unsigned short*)alloc((size_t)32768 * 256 * 2);
    unsigned short* kfull = (unsigned short*)alloc((size_t)32768 * 256 * 2); // -> combined
    unsigned short* kpb  = (unsigned short*)alloc(128 * 256 * 2);
    float* vp    = (float*)alloc(128 * 256 * 4);
    float* s1    = (float*)alloc(128 * 256 * 4);
    float* s0    = (float*)alloc(128 * 4);

    prep_all<<<1806, 256, 0, stream>>>(
        lnfg, lnfb, wq, bq, efpw, efpb, lngg, lngb, wk, bk, wv, bv, wo,
        outcw, outcb, bng, bnb, bnm, bnv, dwk,
        Wb1t, Wb2t, Wot, Woc, dwt, cs1, cst1, cs2, cst2, scv, shv);
    transpose_fg<<<6144, 256, 0, stream>>>(e_f, e_g, ef_bf, eg_bf,
                                           pf, pfq, pg, pgq);
    ln_finalize<<<128, 256, 0, stream>>>(pf, pfq, pg, pgq, mf, rf, mg, rg);
    gemm1_mfma<<<dim3(256, 4), 256, 0, stream>>>(ef_bf, Wb1t, cs1, cst1, mf, rf,
                                                 qbuf, efpbuf);
    gemm2k_mfma<<<dim3(256, 2), 256, 0, stream>>>(eg_bf, Wb2t, cs2, cst2, mg, rg,
                                                  kfull);
    pool_phase<<<256, 256, 0, stream>>>(kfull, eg_bf, rg, mg, kpb, s1, s0);
    vpool_gemm<<<128, 256, 0, stream>>>(s1, s0, lngg, wv, cs2, cst2, vp);
    combined_dw<<<2048, 256, 0, stream>>>(qbuf, kpb, vp, dwt, /*combined=*/kfull);
    gemm34_mfma<<<512, 256, 0, stream>>>(/*combined=*/kfull, Wot, bo, efpbuf,
                                         Woc, scv, shv, outp);
}